// Round 6
// baseline (457.690 us; speedup 1.0000x reference)
//
#include <hip/hip_runtime.h>
#include <hip/hip_bf16.h>

typedef unsigned short u16;
typedef unsigned int u32;
typedef __attribute__((ext_vector_type(8))) __bf16 bf16x8;
typedef __attribute__((ext_vector_type(16))) float f32x16;

#define N_TOK 4096
#define DIMF  514
#define KPAD  544      // 17*32, zero-padded K for QKV gemm
#define OUT3  768
#define OUTD  256
#define RDIM  512
#define FDIM  1542
#define LOG2E 1.4426950408889634f
#define SHIFT2 23.083120654223415f   // 16 * log2(e); q pre-scaled by log2e
#define NCHUNK 8       // split-K chunks over the 4096 keys -> 1536 blocks = 3 full rounds
#define KTILES ((N_TOK / NCHUNK) / 32)

__device__ __forceinline__ bf16x8 ld_frag(const u16* p) {
    return __builtin_bit_cast(bf16x8, *reinterpret_cast<const uint4*>(p));
}
__device__ __forceinline__ u16 f2bf(float x) {
    return __builtin_bit_cast(u16, __float2bfloat16(x));
}
__device__ __forceinline__ float bf2f(u16 u) {
    return __bfloat162float(__builtin_bit_cast(__hip_bfloat16, u));
}
__device__ __forceinline__ f32x16 mfma_b(bf16x8 a, bf16x8 b, f32x16 c) {
    return __builtin_amdgcn_mfma_f32_32x32x16_bf16(a, b, c, 0, 0, 0);
}
// async 16B/lane global -> LDS (LDS dest = wave-uniform base + lane*16)
__device__ __forceinline__ void gl_lds16(const u16* g, u16* l) {
    __builtin_amdgcn_global_load_lds(
        (const __attribute__((address_space(1))) void*)(g),
        (__attribute__((address_space(3))) void*)(l), 16, 0, 0);
}

// ---------------------------------------------------------------- prep: tA
__global__ __launch_bounds__(256, 1) void prep_tA(
    const float* __restrict__ t1, const float* __restrict__ t2,
    const float* __restrict__ t1c, u16* __restrict__ tA)
{
    int idx = blockIdx.x * 256 + threadIdx.x;      // 3*4096*544 exact
    int m = idx / (N_TOK * KPAD);
    int rem = idx - m * (N_TOK * KPAD);
    int row = rem / KPAD;
    int col = rem - row * KPAD;
    const float* t = (m == 0) ? t1 : (m == 1) ? t2 : t1c;
    tA[idx] = (col < DIMF) ? f2bf(t[row * DIMF + col]) : (u16)0;
}

// ---------------------------------------------------------------- prep: W transpose
// Out[m][n][c] = W_m[c][n] (bf16, zero-pad c in [R, OS)); LDS-tiled, coalesced both ways
__global__ __launch_bounds__(256, 1) void transpose_w(
    const float* __restrict__ Wa, const float* __restrict__ Wb,
    const float* __restrict__ Wc, u16* __restrict__ Out,
    int R, int C, int OS)
{
    const int bx = blockIdx.x;   // tile along C (out rows n)
    const int by = blockIdx.y;   // tile along OS (out cols c)
    const int m  = blockIdx.z;
    const float* W = (m == 0) ? Wa : (m == 1) ? Wb : Wc;
    u16* O = Out + (size_t)m * C * OS;

    __shared__ u16 Lt[64 * 72];
    const int tid = threadIdx.x;
    const int c0 = bx * 64, r0 = by * 64;
#pragma unroll
    for (int it = 0; it < 16; it++) {
        int i = it * 256 + tid;
        int ri = i >> 6, ci = i & 63;
        int rr = r0 + ri, cc = c0 + ci;
        float v = (rr < R && cc < C) ? W[rr * C + cc] : 0.f;
        Lt[ci * 72 + ri] = f2bf(v);
    }
    __syncthreads();
#pragma unroll
    for (int it = 0; it < 2; it++) {
        int i = it * 256 + tid;
        int ci = i >> 3, seg = i & 7;
        int n = c0 + ci, col = r0 + seg * 8;
        if (n < C && col < OS)
            *reinterpret_cast<uint4*>(&O[(size_t)n * OS + col]) =
                *reinterpret_cast<const uint4*>(&Lt[ci * 72 + seg * 8]);
    }
}

// ---------------------------------------------------------------- zero O/l accum
__global__ __launch_bounds__(256, 1) void zero_kernel(float4* __restrict__ p, int n4)
{
    int i = blockIdx.x * 256 + threadIdx.x;
    if (i < n4) { float4 z; z.x = z.y = z.z = z.w = 0.f; p[i] = z; }
}

// ---------------------------------------------------------------- QKV gemm
// q stored pre-scaled by log2(e); v stored transposed via LDS (coalesced)
__global__ __launch_bounds__(256, 1) void qkv_gemm(
    const u16* __restrict__ tA, const u16* __restrict__ WqkvT,
    const float* __restrict__ b1, const float* __restrict__ b2, const float* __restrict__ b3,
    u16* __restrict__ qbuf, u16* __restrict__ kbuf, u16* __restrict__ vT)
{
    const int mt = blockIdx.x, nt = blockIdx.y, mod = blockIdx.z;
    const u16* A = tA + mod * (N_TOK * KPAD);
    const u16* B = WqkvT + mod * (OUT3 * KPAD);
    const float* bias = (mod == 0) ? b1 : (mod == 1) ? b2 : b3;

    __shared__ alignas(16) u16 smem[128 * 136];   // Al(5120) + Bl(5120) | Tv(17408)
    u16* Al = smem;
    u16* Bl = smem + 128 * 40;

    const int tid = threadIdx.x;
    const int lane = tid & 63;
    const int w = tid >> 6;
    const int wm = w & 1, wn = w >> 1;
    const int l31 = lane & 31, h = lane >> 5;

    f32x16 acc[2][2];
#pragma unroll
    for (int i = 0; i < 2; i++)
#pragma unroll
        for (int j = 0; j < 2; j++)
#pragma unroll
            for (int r = 0; r < 16; r++) acc[i][j][r] = 0.f;

    for (int kt = 0; kt < KPAD / 32; kt++) {
#pragma unroll
        for (int it = 0; it < 2; it++) {
            int idx = it * 256 + tid;
            int row = idx >> 2;
            int c8 = (idx & 3) * 8;
            uint4 va = *reinterpret_cast<const uint4*>(&A[(mt * 128 + row) * KPAD + kt * 32 + c8]);
            *reinterpret_cast<uint4*>(&Al[row * 40 + c8]) = va;
            uint4 vb = *reinterpret_cast<const uint4*>(&B[(nt * 128 + row) * KPAD + kt * 32 + c8]);
            *reinterpret_cast<uint4*>(&Bl[row * 40 + c8]) = vb;
        }
        __syncthreads();
#pragma unroll
        for (int kc = 0; kc < 2; kc++) {
            bf16x8 af[2], bfr[2];
#pragma unroll
            for (int mr = 0; mr < 2; mr++)
                af[mr] = ld_frag(&Al[(wm * 64 + mr * 32 + l31) * 40 + kc * 16 + h * 8]);
#pragma unroll
            for (int nr = 0; nr < 2; nr++)
                bfr[nr] = ld_frag(&Bl[(wn * 64 + nr * 32 + l31) * 40 + kc * 16 + h * 8]);
#pragma unroll
            for (int mr = 0; mr < 2; mr++)
#pragma unroll
                for (int nr = 0; nr < 2; nr++)
                    acc[mr][nr] = mfma_b(af[mr], bfr[nr], acc[mr][nr]);
        }
        __syncthreads();
    }

    if (nt < 4) {
        // q (cols 0..255, scaled by log2e) and k (cols 256..511), row-major coalesced
        u16* qb = qbuf + mod * (N_TOK * OUTD);
        u16* kb = kbuf + mod * (N_TOK * OUTD);
#pragma unroll
        for (int mr = 0; mr < 2; mr++)
#pragma unroll
            for (int nr = 0; nr < 2; nr++)
#pragma unroll
                for (int r = 0; r < 16; r++) {
                    int row = mt * 128 + wm * 64 + mr * 32 + (r & 3) + 8 * (r >> 2) + 4 * h;
                    int col = nt * 128 + wn * 64 + nr * 32 + l31;
                    float sc = (col < 256) ? LOG2E : 1.0f;
                    u16 bv = f2bf((acc[mr][nr][r] + bias[col]) * sc);
                    if (col < 256) qb[row * OUTD + col] = bv;
                    else           kb[row * OUTD + (col - 256)] = bv;
                }
    } else {
        // v (cols 512..767): transpose 128x128 tile through LDS, coalesced vT stores
        u16* Tv = smem;   // safe: last main-loop iteration ended with __syncthreads
#pragma unroll
        for (int mr = 0; mr < 2; mr++)
#pragma unroll
            for (int nr = 0; nr < 2; nr++)
#pragma unroll
                for (int r = 0; r < 16; r++) {
                    int row_l = wm * 64 + mr * 32 + (r & 3) + 8 * (r >> 2) + 4 * h;
                    int d_l = wn * 64 + nr * 32 + l31;
                    int col_g = nt * 128 + d_l;
                    Tv[d_l * 136 + row_l] = f2bf(acc[mr][nr][r] + bias[col_g]);
                }
        __syncthreads();
        u16* vb = vT + mod * (OUTD * N_TOK);
        const int colbase = (nt - 4) * 128;
#pragma unroll
        for (int it = 0; it < 8; it++) {
            int i = it * 256 + tid;            // 2048 uint4
            int cc = i >> 4, seg = i & 15;
            *reinterpret_cast<uint4*>(&vb[(colbase + cc) * N_TOK + mt * 128 + seg * 8]) =
                *reinterpret_cast<const uint4*>(&Tv[cc * 136 + seg * 8]);
        }
    }
}

// ---------------------------------------------------------------- attention
// Block: 256 thr = 4 waves, 128 q rows (32/wave). Double-buffered async
// fragment-order staging via global_load_lds; waves 0/1 stage K, 2/3 stage V.
// S^T = K Q^T (q pre-scaled by log2e), p = exp2(S - 16*log2e), P^T in regs
// via half-wave shuffles, O^T = V^T P^T. Partials accumulated with fp32
// atomics into Og/lg (zeroed beforehand). VGPR: 128+128acc = 2 waves/SIMD
// cap -> grid sized to 3 exact residency rounds (32*6*8 = 1536 = 3*512).
__global__ __launch_bounds__(256, 2) void attn_kernel(
    const u16* __restrict__ qbuf, const u16* __restrict__ kbuf,
    const u16* __restrict__ vT, float* __restrict__ Og, float* __restrict__ lg)
{
    const int qt = blockIdx.x;   // 0..31  (128-row q tile)
    const int g  = blockIdx.y;   // 0..5
    const int c  = blockIdx.z;   // 0..NCHUNK-1
    const int kv = g >> 1;
    const int mn = (kv == 0) ? 1 : 0;
    const int mx = (kv == 2) ? 1 : 2;
    const int qm = (g & 1) ? mx : mn;

    const u16* Qg = qbuf + qm * (N_TOK * OUTD);
    const u16* Kg = kbuf + kv * (N_TOK * OUTD);
    const u16* Vg = vT + kv * (OUTD * N_TOK);
    float* Op = Og + ((size_t)g * N_TOK + qt * 128) * OUTD;
    float* lp = lg + g * N_TOK + qt * 128;

    // 2 buffers x 32 frags x 512 u16 (1KB per frag: 64 lanes x 16B)
    __shared__ alignas(16) u16 Fbuf[2][32 * 512];

    const int tid = threadIdx.x;
    const int lane = tid & 63;
    const int w = tid >> 6;           // 0..3
    const int l31 = lane & 31, h = lane >> 5;
    const int q0 = qt * 128 + w * 32;

    auto stage = [&](int k0, u16* dst) {
        if (w < 2) {
#pragma unroll
            for (int fi = 0; fi < 8; fi++) {
                int dc = w * 8 + fi;
                gl_lds16(&Kg[(k0 + l31) * OUTD + dc * 16 + h * 8], dst + dc * 512);
            }
        } else {
#pragma unroll
            for (int fi = 0; fi < 8; fi++) {
                int f = (w - 2) * 8 + fi;           // 0..15
                int nb = f >> 1, half = f & 1;
                gl_lds16(&Vg[(nb * 32 + l31) * N_TOK + k0 + half * 16 + h * 8],
                         dst + (16 + f) * 512);
            }
        }
    };

    const int k0base = c * (N_TOK / NCHUNK);

    stage(k0base, Fbuf[0]);

    bf16x8 qf[16];
#pragma unroll
    for (int dc = 0; dc < 16; dc++)
        qf[dc] = ld_frag(&Qg[(q0 + l31) * OUTD + dc * 16 + h * 8]);

    f32x16 Oacc[8];
#pragma unroll
    for (int nb = 0; nb < 8; nb++)
#pragma unroll
        for (int r = 0; r < 16; r++) Oacc[nb][r] = 0.f;
    float lsum = 0.f;

    __syncthreads();   // tile 0 resident

    for (int kt = 0; kt < KTILES; kt++) {
        const int p = kt & 1;
        if (kt + 1 < KTILES) stage(k0base + (kt + 1) * 32, Fbuf[p ^ 1]);
        const u16* FB = Fbuf[p];

        // S^T[key][q] = K Q^T
        f32x16 S;
#pragma unroll
        for (int r = 0; r < 16; r++) S[r] = 0.f;
#pragma unroll
        for (int dc = 0; dc < 16; dc++) {
            bf16x8 kf = ld_frag(&FB[dc * 512 + lane * 8]);
            S = mfma_b(kf, qf[dc], S);
        }

        // p = 2^(S - 16*log2e)  (q was pre-scaled by log2e)
        float e[16];
#pragma unroll
        for (int r = 0; r < 16; r++) { e[r] = exp2f(S[r] - SHIFT2); lsum += e[r]; }
        u32 pk[8];
#pragma unroll
        for (int i = 0; i < 8; i++)
            pk[i] = (u32)f2bf(e[2 * i]) | ((u32)f2bf(e[2 * i + 1]) << 16);
        u32 x[8];
#pragma unroll
        for (int i = 0; i < 8; i++)
            x[i] = (u32)__shfl_xor((int)pk[i], 32, 64);
        uint4 b0, b1;
        b0.x = h ? x[2] : pk[0]; b0.y = h ? x[3] : pk[1];
        b0.z = h ? pk[2] : x[0]; b0.w = h ? pk[3] : x[1];
        b1.x = h ? x[6] : pk[4]; b1.y = h ? x[7] : pk[5];
        b1.z = h ? pk[6] : x[4]; b1.w = h ? pk[7] : x[5];
        bf16x8 pb0 = __builtin_bit_cast(bf16x8, b0);
        bf16x8 pb1 = __builtin_bit_cast(bf16x8, b1);

        // O^T[d][q] += V^T[d][k] P^T[k][q]
#pragma unroll
        for (int nb = 0; nb < 8; nb++) {
            bf16x8 vf0 = ld_frag(&FB[(16 + 2 * nb) * 512 + lane * 8]);
            bf16x8 vf1 = ld_frag(&FB[(17 + 2 * nb) * 512 + lane * 8]);
            Oacc[nb] = mfma_b(vf0, pb0, Oacc[nb]);
            Oacc[nb] = mfma_b(vf1, pb1, Oacc[nb]);
        }
        __syncthreads();
    }

    // l partial: combine h-halves, atomically accumulate
    lsum += __shfl_xor(lsum, 32, 64);
    if (lane < 32) atomicAdd(&lp[w * 32 + lane], lsum);

    // transpose O^T -> [q][d] through wave-private LDS scratch, atomic fp32 add
    float* Tb = reinterpret_cast<float*>(&Fbuf[0][0]) + w * (32 * 33);
#pragma unroll
    for (int nb = 0; nb < 8; nb++) {
#pragma unroll
        for (int r = 0; r < 16; r++)
            Tb[((r & 3) + 8 * (r >> 2) + 4 * h) * 33 + l31] = Oacc[nb][r];
        __builtin_amdgcn_s_waitcnt(0);  // lgkm drain before re-read (wave-private)
#pragma unroll
        for (int qq = 0; qq < 16; qq++) {
            float v = Tb[l31 * 33 + qq * 2 + h];
            atomicAdd(&Op[(w * 32 + qq * 2 + h) * OUTD + nb * 32 + l31], v);
        }
        __builtin_amdgcn_s_waitcnt(0);
    }
}

// ---------------------------------------------------------------- combine
// o = Og/lg + k_residual -> rbuf bf16 [qm][q][slot*256+d]
__global__ __launch_bounds__(256, 1) void combine_kernel(
    const float* __restrict__ Og, const float* __restrict__ lg,
    const u16* __restrict__ kbuf, u16* __restrict__ rbuf)
{
    const int q = blockIdx.x;
    const int g = blockIdx.y;
    const int d = threadIdx.x;
    const int kv = g >> 1;
    const int mn = (kv == 0) ? 1 : 0;
    const int mx = (kv == 2) ? 1 : 2;
    const int qm = (g & 1) ? mx : mn;
    const int sm = (qm == 0) ? 1 : 0;
    const int slot = (kv == sm) ? 0 : 1;

    float o = Og[((size_t)g * N_TOK + q) * OUTD + d];
    float l = lg[g * N_TOK + q];
    float res = o / l + bf2f(kbuf[qm * (N_TOK * OUTD) + q * OUTD + d]);
    rbuf[qm * (size_t)(N_TOK * RDIM) + q * RDIM + slot * OUTD + d] = f2bf(res);
}

// ---------------------------------------------------------------- out proj
__global__ __launch_bounds__(256, 1) void proj_gemm(
    const u16* __restrict__ rbuf, const u16* __restrict__ WoT,
    const float* __restrict__ bo1, const float* __restrict__ bo2, const float* __restrict__ bo3,
    const float* __restrict__ t1, const float* __restrict__ t2, const float* __restrict__ t1c,
    float* __restrict__ feat)
{
    const int mt = blockIdx.x, nt = blockIdx.y, mod = blockIdx.z;
    const u16* A = rbuf + mod * (N_TOK * RDIM);
    const u16* B = WoT + mod * (DIMF * RDIM);
    const float* bias = (mod == 0) ? bo1 : (mod == 1) ? bo2 : bo3;
    const float* tres = (mod == 0) ? t1 : (mod == 1) ? t2 : t1c;

    __shared__ alignas(16) u16 Al[128 * 40];
    __shared__ alignas(16) u16 Bl[128 * 40];

    const int tid = threadIdx.x;
    const int lane = tid & 63;
    const int w = tid >> 6;
    const int wm = w & 1, wn = w >> 1;
    const int l31 = lane & 31, h = lane >> 5;

    f32x16 acc[2][2];
#pragma unroll
    for (int i = 0; i < 2; i++)
#pragma unroll
        for (int j = 0; j < 2; j++)
#pragma unroll
            for (int r = 0; r < 16; r++) acc[i][j][r] = 0.f;

    for (int kt = 0; kt < RDIM / 32; kt++) {
#pragma unroll
        for (int it = 0; it < 2; it++) {
            int idx = it * 256 + tid;
            int row = idx >> 2;
            int c8 = (idx & 3) * 8;
            uint4 va = *reinterpret_cast<const uint4*>(&A[(mt * 128 + row) * RDIM + kt * 32 + c8]);
            *reinterpret_cast<uint4*>(&Al[row * 40 + c8]) = va;
            int n = nt * 128 + row;
            uint4 vb;
            if (n < DIMF) vb = *reinterpret_cast<const uint4*>(&B[n * RDIM + kt * 32 + c8]);
            else { vb.x = vb.y = vb.z = vb.w = 0u; }
            *reinterpret_cast<uint4*>(&Bl[row * 40 + c8]) = vb;
        }
        __syncthreads();
#pragma unroll
        for (int kc = 0; kc < 2; kc++) {
            bf16x8 af[2], bfr[2];
#pragma unroll
            for (int mr = 0; mr < 2; mr++)
                af[mr] = ld_frag(&Al[(wm * 64 + mr * 32 + l31) * 40 + kc * 16 + h * 8]);
#pragma unroll
            for (int nr = 0; nr < 2; nr++)
                bfr[nr] = ld_frag(&Bl[(wn * 64 + nr * 32 + l31) * 40 + kc * 16 + h * 8]);
#pragma unroll
            for (int mr = 0; mr < 2; mr++)
#pragma unroll
                for (int nr = 0; nr < 2; nr++)
                    acc[mr][nr] = mfma_b(af[mr], bfr[nr], acc[mr][nr]);
        }
        __syncthreads();
    }

#pragma unroll
    for (int mr = 0; mr < 2; mr++)
#pragma unroll
        for (int nr = 0; nr < 2; nr++)
#pragma unroll
            for (int r = 0; r < 16; r++) {
                int row = mt * 128 + wm * 64 + mr * 32 + (r & 3) + 8 * (r >> 2) + 4 * h;
                int col = nt * 128 + wn * 64 + nr * 32 + l31;
                if (col < DIMF) {
                    float v = acc[mr][nr][r] + bias[col] + tres[row * DIMF + col];
                    feat[row * FDIM + mod * DIMF + col] = v;
                }
            }
}

// ---------------------------------------------------------------- LN + head
__global__ __launch_bounds__(256, 1) void ln_head(
    const float* __restrict__ feat, const float* __restrict__ gam,
    const float* __restrict__ bet, const float* __restrict__ Wh,
    const float* __restrict__ bh, float* __restrict__ out)
{
    const int row = blockIdx.x;
    const float* x = feat + row * FDIM;
    const int tid = threadIdx.x;
    float v[7];
    float s = 0.f, ss = 0.f;
#pragma unroll
    for (int i = 0; i < 7; i++) {
        int idx = tid + i * 256;
        float val = (idx < FDIM) ? x[idx] : 0.f;
        v[i] = val; s += val; ss += val * val;
    }
#pragma unroll
    for (int m = 1; m < 64; m <<= 1) { s += __shfl_xor(s, m, 64); ss += __shfl_xor(ss, m, 64); }
    __shared__ float red[8];
    const int w = tid >> 6, lane = tid & 63;
    if (lane == 0) { red[w] = s; red[4 + w] = ss; }
    __syncthreads();
    s = red[0] + red[1] + red[2] + red[3];
    ss = red[4] + red[5] + red[6] + red[7];
    const float mu = s / (float)FDIM;
    const float var = ss / (float)FDIM - mu * mu;
    const float rstd = rsqrtf(var + 1e-5f);
    float a0 = 0.f, a1 = 0.f;
#pragma unroll
    for (int i = 0; i < 7; i++) {
        int idx = tid + i * 256;
        if (idx < FDIM) {
            float nv = (v[i] - mu) * rstd * gam[idx] + bet[idx];
            a0 += nv * Wh[idx * 2];
            a1 += nv * Wh[idx * 2 + 1];
        }
    }
#pragma unroll
    for (int m = 1; m < 64; m <<= 1) { a0 += __shfl_xor(a0, m, 64); a1 += __shfl_xor(a1, m, 64); }
    __shared__ float red2[8];
    if (lane == 0) { red2[w] = a0; red2[4 + w] = a1; }
    __syncthreads();
    if (tid == 0) {
        out[row * 2 + 0] = red2[0] + red2[1] + red2[2] + red2[3] + bh[0];
        out[row * 2 + 1] = red2[4] + red2[5] + red2[6] + red2[7] + bh[1];
    }
}

// ---------------------------------------------------------------- launch
extern "C" void kernel_launch(void* const* d_in, const int* in_sizes, int n_in,
                              void* d_out, int out_size, void* d_ws, size_t ws_size,
                              hipStream_t stream)
{
    const float* t1    = (const float*)d_in[0];
    const float* t2    = (const float*)d_in[1];
    const float* t1c   = (const float*)d_in[2];
    const float* Wqkv1 = (const float*)d_in[3];
    const float* bqkv1 = (const float*)d_in[4];
    const float* Wqkv2 = (const float*)d_in[5];
    const float* bqkv2 = (const float*)d_in[6];
    const float* Wqkv3 = (const float*)d_in[7];
    const float* bqkv3 = (const float*)d_in[8];
    const float* Wo1   = (const float*)d_in[9];
    const float* bo1   = (const float*)d_in[10];
    const float* Wo2   = (const float*)d_in[11];
    const float* bo2   = (const float*)d_in[12];
    const float* Wo3   = (const float*)d_in[13];
    const float* bo3   = (const float*)d_in[14];
    const float* ln_g  = (const float*)d_in[15];
    const float* ln_b  = (const float*)d_in[16];
    const float* Wh    = (const float*)d_in[17];
    const float* bh    = (const float*)d_in[18];

    char* ws = (char*)d_ws;
    size_t off = 0;
    u16* tA    = (u16*)(ws + off); off += (size_t)3 * N_TOK * KPAD * 2;
    u16* WqkvT = (u16*)(ws + off); off += (size_t)3 * OUT3 * KPAD * 2;
    u16* WoT   = (u16*)(ws + off); off += (size_t)3 * DIMF * RDIM * 2;
    u16* qbuf  = (u16*)(ws + off); off += (size_t)3 * N_TOK * OUTD * 2;
    u16* kbuf  = (u16*)(ws + off); off += (size_t)3 * N_TOK * OUTD * 2;
    u16* vT    = (u16*)(ws + off); off += (size_t)3 * OUTD * N_TOK * 2;
    u16* rbuf  = (u16*)(ws + off); off += (size_t)3 * N_TOK * RDIM * 2;
    float* Og  = (float*)(ws + off); off += (size_t)6 * N_TOK * OUTD * 4;
    float* lg  = (float*)(ws + off); off += (size_t)6 * N_TOK * 4;   // contiguous after Og

    float* out  = (float*)d_out;
    float* feat = out + N_TOK * 2;

    prep_tA<<<(3 * N_TOK * KPAD) / 256, 256, 0, stream>>>(t1, t2, t1c, tA);

    transpose_w<<<dim3(12, 9, 3), 256, 0, stream>>>(
        Wqkv1, Wqkv2, Wqkv3, WqkvT, DIMF, OUT3, KPAD);      // [768][544]
    transpose_w<<<dim3(9, 8, 3), 256, 0, stream>>>(
        Wo1, Wo2, Wo3, WoT, RDIM, DIMF, RDIM);              // [514][512]

    const int zero_n4 = (6 * N_TOK * OUTD + 6 * N_TOK) / 4;
    zero_kernel<<<(zero_n4 + 255) / 256, 256, 0, stream>>>((float4*)Og, zero_n4);

    qkv_gemm<<<dim3(32, 6, 3), 256, 0, stream>>>(
        tA, WqkvT, bqkv1, bqkv2, bqkv3, qbuf, kbuf, vT);

    attn_kernel<<<dim3(32, 6, NCHUNK), 256, 0, stream>>>(qbuf, kbuf, vT, Og, lg);

    combine_kernel<<<dim3(N_TOK, 6), 256, 0, stream>>>(Og, lg, kbuf, rbuf);

    proj_gemm<<<dim3(32, 5, 3), 256, 0, stream>>>(
        rbuf, WoT, bo1, bo2, bo3, t1, t2, t1c, feat);

    ln_head<<<4096, 256, 0, stream>>>(feat, ln_g, ln_b, Wh, bh, out);
}

// Round 7
// 348.040 us; speedup vs baseline: 1.3150x; 1.3150x over previous
//
#include <hip/hip_runtime.h>
#include <hip/hip_bf16.h>

typedef unsigned short u16;
typedef unsigned int u32;
typedef __attribute__((ext_vector_type(8))) __bf16 bf16x8;
typedef __attribute__((ext_vector_type(16))) float f32x16;

#define N_TOK 4096
#define DIMF  514
#define KPAD  544      // 17*32, zero-padded K for QKV gemm
#define OUT3  768
#define OUTD  256
#define RDIM  512
#define FDIM  1542
#define LOG2E 1.4426950408889634f
#define SHIFT2 23.083120654223415f   // 16 * log2(e); q pre-scaled by log2e
#define NCHUNK 4       // split-K chunks; Opart = 50 MB (ws-proven at R4/R5)
#define KTILES ((N_TOK / NCHUNK) / 32)

__device__ __forceinline__ bf16x8 ld_frag(const u16* p) {
    return __builtin_bit_cast(bf16x8, *reinterpret_cast<const uint4*>(p));
}
__device__ __forceinline__ u16 f2bf(float x) {
    return __builtin_bit_cast(u16, __float2bfloat16(x));
}
__device__ __forceinline__ float bf2f(u16 u) {
    return __bfloat162float(__builtin_bit_cast(__hip_bfloat16, u));
}
__device__ __forceinline__ f32x16 mfma_b(bf16x8 a, bf16x8 b, f32x16 c) {
    return __builtin_amdgcn_mfma_f32_32x32x16_bf16(a, b, c, 0, 0, 0);
}
// async 16B/lane global -> LDS (LDS dest = wave-uniform base + lane*16)
__device__ __forceinline__ void gl_lds16(const u16* g, u16* l) {
    __builtin_amdgcn_global_load_lds(
        (const __attribute__((address_space(1))) void*)(g),
        (__attribute__((address_space(3))) void*)(l), 16, 0, 0);
}

// ---------------------------------------------------------------- prep: tA
__global__ __launch_bounds__(256, 1) void prep_tA(
    const float* __restrict__ t1, const float* __restrict__ t2,
    const float* __restrict__ t1c, u16* __restrict__ tA)
{
    int idx = blockIdx.x * 256 + threadIdx.x;      // 3*4096*544 exact
    int m = idx / (N_TOK * KPAD);
    int rem = idx - m * (N_TOK * KPAD);
    int row = rem / KPAD;
    int col = rem - row * KPAD;
    const float* t = (m == 0) ? t1 : (m == 1) ? t2 : t1c;
    tA[idx] = (col < DIMF) ? f2bf(t[row * DIMF + col]) : (u16)0;
}

// ---------------------------------------------------------------- prep: W transpose
// Out[m][n][c] = W_m[c][n] (bf16, zero-pad c in [R, OS)); LDS-tiled, coalesced both ways
__global__ __launch_bounds__(256, 1) void transpose_w(
    const float* __restrict__ Wa, const float* __restrict__ Wb,
    const float* __restrict__ Wc, u16* __restrict__ Out,
    int R, int C, int OS)
{
    const int bx = blockIdx.x;   // tile along C (out rows n)
    const int by = blockIdx.y;   // tile along OS (out cols c)
    const int m  = blockIdx.z;
    const float* W = (m == 0) ? Wa : (m == 1) ? Wb : Wc;
    u16* O = Out + (size_t)m * C * OS;

    __shared__ u16 Lt[64 * 72];
    const int tid = threadIdx.x;
    const int c0 = bx * 64, r0 = by * 64;
#pragma unroll
    for (int it = 0; it < 16; it++) {
        int i = it * 256 + tid;
        int ri = i >> 6, ci = i & 63;
        int rr = r0 + ri, cc = c0 + ci;
        float v = (rr < R && cc < C) ? W[rr * C + cc] : 0.f;
        Lt[ci * 72 + ri] = f2bf(v);
    }
    __syncthreads();
#pragma unroll
    for (int it = 0; it < 2; it++) {
        int i = it * 256 + tid;
        int ci = i >> 3, seg = i & 7;
        int n = c0 + ci, col = r0 + seg * 8;
        if (n < C && col < OS)
            *reinterpret_cast<uint4*>(&O[(size_t)n * OS + col]) =
                *reinterpret_cast<const uint4*>(&Lt[ci * 72 + seg * 8]);
    }
}

// ---------------------------------------------------------------- QKV gemm
// q stored pre-scaled by log2(e); v stored transposed via LDS (coalesced)
__global__ __launch_bounds__(256, 1) void qkv_gemm(
    const u16* __restrict__ tA, const u16* __restrict__ WqkvT,
    const float* __restrict__ b1, const float* __restrict__ b2, const float* __restrict__ b3,
    u16* __restrict__ qbuf, u16* __restrict__ kbuf, u16* __restrict__ vT)
{
    const int mt = blockIdx.x, nt = blockIdx.y, mod = blockIdx.z;
    const u16* A = tA + mod * (N_TOK * KPAD);
    const u16* B = WqkvT + mod * (OUT3 * KPAD);
    const float* bias = (mod == 0) ? b1 : (mod == 1) ? b2 : b3;

    __shared__ alignas(16) u16 smem[128 * 136];   // Al(5120) + Bl(5120) | Tv(17408)
    u16* Al = smem;
    u16* Bl = smem + 128 * 40;

    const int tid = threadIdx.x;
    const int lane = tid & 63;
    const int w = tid >> 6;
    const int wm = w & 1, wn = w >> 1;
    const int l31 = lane & 31, h = lane >> 5;

    f32x16 acc[2][2];
#pragma unroll
    for (int i = 0; i < 2; i++)
#pragma unroll
        for (int j = 0; j < 2; j++)
#pragma unroll
            for (int r = 0; r < 16; r++) acc[i][j][r] = 0.f;

    for (int kt = 0; kt < KPAD / 32; kt++) {
#pragma unroll
        for (int it = 0; it < 2; it++) {
            int idx = it * 256 + tid;
            int row = idx >> 2;
            int c8 = (idx & 3) * 8;
            uint4 va = *reinterpret_cast<const uint4*>(&A[(mt * 128 + row) * KPAD + kt * 32 + c8]);
            *reinterpret_cast<uint4*>(&Al[row * 40 + c8]) = va;
            uint4 vb = *reinterpret_cast<const uint4*>(&B[(nt * 128 + row) * KPAD + kt * 32 + c8]);
            *reinterpret_cast<uint4*>(&Bl[row * 40 + c8]) = vb;
        }
        __syncthreads();
#pragma unroll
        for (int kc = 0; kc < 2; kc++) {
            bf16x8 af[2], bfr[2];
#pragma unroll
            for (int mr = 0; mr < 2; mr++)
                af[mr] = ld_frag(&Al[(wm * 64 + mr * 32 + l31) * 40 + kc * 16 + h * 8]);
#pragma unroll
            for (int nr = 0; nr < 2; nr++)
                bfr[nr] = ld_frag(&Bl[(wn * 64 + nr * 32 + l31) * 40 + kc * 16 + h * 8]);
#pragma unroll
            for (int mr = 0; mr < 2; mr++)
#pragma unroll
                for (int nr = 0; nr < 2; nr++)
                    acc[mr][nr] = mfma_b(af[mr], bfr[nr], acc[mr][nr]);
        }
        __syncthreads();
    }

    if (nt < 4) {
        // q (cols 0..255, scaled by log2e) and k (cols 256..511), row-major coalesced
        u16* qb = qbuf + mod * (N_TOK * OUTD);
        u16* kb = kbuf + mod * (N_TOK * OUTD);
#pragma unroll
        for (int mr = 0; mr < 2; mr++)
#pragma unroll
            for (int nr = 0; nr < 2; nr++)
#pragma unroll
                for (int r = 0; r < 16; r++) {
                    int row = mt * 128 + wm * 64 + mr * 32 + (r & 3) + 8 * (r >> 2) + 4 * h;
                    int col = nt * 128 + wn * 64 + nr * 32 + l31;
                    float sc = (col < 256) ? LOG2E : 1.0f;
                    u16 bv = f2bf((acc[mr][nr][r] + bias[col]) * sc);
                    if (col < 256) qb[row * OUTD + col] = bv;
                    else           kb[row * OUTD + (col - 256)] = bv;
                }
    } else {
        // v (cols 512..767): transpose 128x128 tile through LDS, coalesced vT stores
        u16* Tv = smem;   // safe: last main-loop iteration ended with __syncthreads
#pragma unroll
        for (int mr = 0; mr < 2; mr++)
#pragma unroll
            for (int nr = 0; nr < 2; nr++)
#pragma unroll
                for (int r = 0; r < 16; r++) {
                    int row_l = wm * 64 + mr * 32 + (r & 3) + 8 * (r >> 2) + 4 * h;
                    int d_l = wn * 64 + nr * 32 + l31;
                    int col_g = nt * 128 + d_l;
                    Tv[d_l * 136 + row_l] = f2bf(acc[mr][nr][r] + bias[col_g]);
                }
        __syncthreads();
        u16* vb = vT + mod * (OUTD * N_TOK);
        const int colbase = (nt - 4) * 128;
#pragma unroll
        for (int it = 0; it < 8; it++) {
            int i = it * 256 + tid;            // 2048 uint4
            int cc = i >> 4, seg = i & 15;
            *reinterpret_cast<uint4*>(&vb[(colbase + cc) * N_TOK + mt * 128 + seg * 8]) =
                *reinterpret_cast<const uint4*>(&Tv[cc * 136 + seg * 8]);
        }
    }
}

// ---------------------------------------------------------------- attention
// R5-proven structure: 256 thr = 4 waves, 128 q rows (32/wave). Double-buffered
// async fragment-order staging via global_load_lds (frag f at f*1024B + lane*16B);
// waves 0/1 stage K frags, 2/3 stage V frags. One barrier per tile.
// S^T = K Q^T (q pre-scaled by log2e), p = exp2(S - 16*log2e), P^T built in
// registers via half-wave shuffles, O^T = V^T P^T. bf16 partials to Opart
// (NO atomics -- R6's fp32 atomicAdd epilogue tripled WRITE_SIZE and regressed).
// VGPR: 128 arch + 128 acc = 2 waves/SIMD cap; do NOT raise min-waves (R3 spill).
__global__ __launch_bounds__(256, 2) void attn_kernel(
    const u16* __restrict__ qbuf, const u16* __restrict__ kbuf,
    const u16* __restrict__ vT, u16* __restrict__ Opart, float* __restrict__ lpart)
{
    const int qt = blockIdx.x;   // 0..31  (128-row q tile)
    const int g  = blockIdx.y;   // 0..5
    const int c  = blockIdx.z;   // 0..NCHUNK-1
    const int kv = g >> 1;
    const int mn = (kv == 0) ? 1 : 0;
    const int mx = (kv == 2) ? 1 : 2;
    const int qm = (g & 1) ? mx : mn;

    const u16* Qg = qbuf + qm * (N_TOK * OUTD);
    const u16* Kg = kbuf + kv * (N_TOK * OUTD);
    const u16* Vg = vT + kv * (OUTD * N_TOK);
    u16* Op = Opart + ((size_t)(c * 6 + g) * N_TOK + qt * 128) * OUTD;
    float* lp = lpart + (c * 6 + g) * N_TOK + qt * 128;

    // 2 buffers x 32 frags x 512 u16 (1KB per frag: 64 lanes x 16B)
    __shared__ alignas(16) u16 Fbuf[2][32 * 512];

    const int tid = threadIdx.x;
    const int lane = tid & 63;
    const int w = tid >> 6;           // 0..3
    const int l31 = lane & 31, h = lane >> 5;
    const int q0 = qt * 128 + w * 32;

    auto stage = [&](int k0, u16* dst) {
        if (w < 2) {
#pragma unroll
            for (int fi = 0; fi < 8; fi++) {
                int dc = w * 8 + fi;
                gl_lds16(&Kg[(k0 + l31) * OUTD + dc * 16 + h * 8], dst + dc * 512);
            }
        } else {
#pragma unroll
            for (int fi = 0; fi < 8; fi++) {
                int f = (w - 2) * 8 + fi;           // 0..15
                int nb = f >> 1, half = f & 1;
                gl_lds16(&Vg[(nb * 32 + l31) * N_TOK + k0 + half * 16 + h * 8],
                         dst + (16 + f) * 512);
            }
        }
    };

    const int k0base = c * (N_TOK / NCHUNK);

    stage(k0base, Fbuf[0]);

    bf16x8 qf[16];
#pragma unroll
    for (int dc = 0; dc < 16; dc++)
        qf[dc] = ld_frag(&Qg[(q0 + l31) * OUTD + dc * 16 + h * 8]);

    f32x16 Oacc[8];
#pragma unroll
    for (int nb = 0; nb < 8; nb++)
#pragma unroll
        for (int r = 0; r < 16; r++) Oacc[nb][r] = 0.f;
    float lsum = 0.f;

    __syncthreads();   // tile 0 resident

    for (int kt = 0; kt < KTILES; kt++) {
        const int p = kt & 1;
        if (kt + 1 < KTILES) stage(k0base + (kt + 1) * 32, Fbuf[p ^ 1]);
        const u16* FB = Fbuf[p];

        // S^T[key][q] = K Q^T   (16 frag reads, conflict-free lane*16)
        f32x16 S;
#pragma unroll
        for (int r = 0; r < 16; r++) S[r] = 0.f;
#pragma unroll
        for (int dc = 0; dc < 16; dc++) {
            bf16x8 kf = ld_frag(&FB[dc * 512 + lane * 8]);
            S = mfma_b(kf, qf[dc], S);
        }

        // p = 2^(S - 16*log2e)  (q was pre-scaled by log2e)
        float e[16];
#pragma unroll
        for (int r = 0; r < 16; r++) { e[r] = exp2f(S[r] - SHIFT2); lsum += e[r]; }
        u32 pk[8];
#pragma unroll
        for (int i = 0; i < 8; i++)
            pk[i] = (u32)f2bf(e[2 * i]) | ((u32)f2bf(e[2 * i + 1]) << 16);
        u32 x[8];
#pragma unroll
        for (int i = 0; i < 8; i++)
            x[i] = (u32)__shfl_xor((int)pk[i], 32, 64);
        uint4 b0, b1;
        b0.x = h ? x[2] : pk[0]; b0.y = h ? x[3] : pk[1];
        b0.z = h ? pk[2] : x[0]; b0.w = h ? pk[3] : x[1];
        b1.x = h ? x[6] : pk[4]; b1.y = h ? x[7] : pk[5];
        b1.z = h ? pk[6] : x[4]; b1.w = h ? pk[7] : x[5];
        bf16x8 pb0 = __builtin_bit_cast(bf16x8, b0);
        bf16x8 pb1 = __builtin_bit_cast(bf16x8, b1);

        // O^T[d][q] += V^T[d][k] P^T[k][q]
#pragma unroll
        for (int nb = 0; nb < 8; nb++) {
            bf16x8 vf0 = ld_frag(&FB[(16 + 2 * nb) * 512 + lane * 8]);
            bf16x8 vf1 = ld_frag(&FB[(17 + 2 * nb) * 512 + lane * 8]);
            Oacc[nb] = mfma_b(vf0, pb0, Oacc[nb]);
            Oacc[nb] = mfma_b(vf1, pb1, Oacc[nb]);
        }
        __syncthreads();
    }

    // l partial: combine h-halves (column q = l31)
    lsum += __shfl_xor(lsum, 32, 64);
    if (lane < 32) lp[w * 32 + lane] = lsum;

    // transpose O^T -> [q][d] through wave-private LDS scratch, store bf16
    float* Tb = reinterpret_cast<float*>(&Fbuf[0][0]) + w * (32 * 33);
#pragma unroll
    for (int nb = 0; nb < 8; nb++) {
#pragma unroll
        for (int r = 0; r < 16; r++)
            Tb[((r & 3) + 8 * (r >> 2) + 4 * h) * 33 + l31] = Oacc[nb][r];
        __builtin_amdgcn_s_waitcnt(0);  // lgkm drain before re-read (wave-private)
#pragma unroll
        for (int qq = 0; qq < 16; qq++) {
            float v = Tb[l31 * 33 + qq * 2 + h];
            Op[(w * 32 + qq * 2 + h) * OUTD + nb * 32 + l31] = f2bf(v);
        }
        __builtin_amdgcn_s_waitcnt(0);
    }
}

// ---------------------------------------------------------------- combine
// o = sum(O_c)/sum(l_c) + k_residual -> rbuf bf16 [qm][q][slot*256+d]
__global__ __launch_bounds__(256, 1) void combine_kernel(
    const u16* __restrict__ Opart, const float* __restrict__ lpart,
    const u16* __restrict__ kbuf, u16* __restrict__ rbuf)
{
    const int q = blockIdx.x;
    const int g = blockIdx.y;
    const int d = threadIdx.x;
    const int kv = g >> 1;
    const int mn = (kv == 0) ? 1 : 0;
    const int mx = (kv == 2) ? 1 : 2;
    const int qm = (g & 1) ? mx : mn;
    const int sm = (qm == 0) ? 1 : 0;
    const int slot = (kv == sm) ? 0 : 1;

    float o = 0.f, l = 0.f;
#pragma unroll
    for (int c = 0; c < NCHUNK; c++) {
        o += bf2f(Opart[((size_t)(c * 6 + g) * N_TOK + q) * OUTD + d]);
        l += lpart[(c * 6 + g) * N_TOK + q];
    }
    float res = o / l + bf2f(kbuf[qm * (N_TOK * OUTD) + q * OUTD + d]);
    rbuf[qm * (size_t)(N_TOK * RDIM) + q * RDIM + slot * OUTD + d] = f2bf(res);
}

// ---------------------------------------------------------------- out proj
__global__ __launch_bounds__(256, 1) void proj_gemm(
    const u16* __restrict__ rbuf, const u16* __restrict__ WoT,
    const float* __restrict__ bo1, const float* __restrict__ bo2, const float* __restrict__ bo3,
    const float* __restrict__ t1, const float* __restrict__ t2, const float* __restrict__ t1c,
    float* __restrict__ feat)
{
    const int mt = blockIdx.x, nt = blockIdx.y, mod = blockIdx.z;
    const u16* A = rbuf + mod * (N_TOK * RDIM);
    const u16* B = WoT + mod * (DIMF * RDIM);
    const float* bias = (mod == 0) ? bo1 : (mod == 1) ? bo2 : bo3;
    const float* tres = (mod == 0) ? t1 : (mod == 1) ? t2 : t1c;

    __shared__ alignas(16) u16 Al[128 * 40];
    __shared__ alignas(16) u16 Bl[128 * 40];

    const int tid = threadIdx.x;
    const int lane = tid & 63;
    const int w = tid >> 6;
    const int wm = w & 1, wn = w >> 1;
    const int l31 = lane & 31, h = lane >> 5;

    f32x16 acc[2][2];
#pragma unroll
    for (int i = 0; i < 2; i++)
#pragma unroll
        for (int j = 0; j < 2; j++)
#pragma unroll
            for (int r = 0; r < 16; r++) acc[i][j][r] = 0.f;

    for (int kt = 0; kt < RDIM / 32; kt++) {
#pragma unroll
        for (int it = 0; it < 2; it++) {
            int idx = it * 256 + tid;
            int row = idx >> 2;
            int c8 = (idx & 3) * 8;
            uint4 va = *reinterpret_cast<const uint4*>(&A[(mt * 128 + row) * RDIM + kt * 32 + c8]);
            *reinterpret_cast<uint4*>(&Al[row * 40 + c8]) = va;
            int n = nt * 128 + row;
            uint4 vb;
            if (n < DIMF) vb = *reinterpret_cast<const uint4*>(&B[n * RDIM + kt * 32 + c8]);
            else { vb.x = vb.y = vb.z = vb.w = 0u; }
            *reinterpret_cast<uint4*>(&Bl[row * 40 + c8]) = vb;
        }
        __syncthreads();
#pragma unroll
        for (int kc = 0; kc < 2; kc++) {
            bf16x8 af[2], bfr[2];
#pragma unroll
            for (int mr = 0; mr < 2; mr++)
                af[mr] = ld_frag(&Al[(wm * 64 + mr * 32 + l31) * 40 + kc * 16 + h * 8]);
#pragma unroll
            for (int nr = 0; nr < 2; nr++)
                bfr[nr] = ld_frag(&Bl[(wn * 64 + nr * 32 + l31) * 40 + kc * 16 + h * 8]);
#pragma unroll
            for (int mr = 0; mr < 2; mr++)
#pragma unroll
                for (int nr = 0; nr < 2; nr++)
                    acc[mr][nr] = mfma_b(af[mr], bfr[nr], acc[mr][nr]);
        }
        __syncthreads();
    }

#pragma unroll
    for (int mr = 0; mr < 2; mr++)
#pragma unroll
        for (int nr = 0; nr < 2; nr++)
#pragma unroll
            for (int r = 0; r < 16; r++) {
                int row = mt * 128 + wm * 64 + mr * 32 + (r & 3) + 8 * (r >> 2) + 4 * h;
                int col = nt * 128 + wn * 64 + nr * 32 + l31;
                if (col < DIMF) {
                    float v = acc[mr][nr][r] + bias[col] + tres[row * DIMF + col];
                    feat[row * FDIM + mod * DIMF + col] = v;
                }
            }
}

// ---------------------------------------------------------------- LN + head
__global__ __launch_bounds__(256, 1) void ln_head(
    const float* __restrict__ feat, const float* __restrict__ gam,
    const float* __restrict__ bet, const float* __restrict__ Wh,
    const float* __restrict__ bh, float* __restrict__ out)
{
    const int row = blockIdx.x;
    const float* x = feat + row * FDIM;
    const int tid = threadIdx.x;
    float v[7];
    float s = 0.f, ss = 0.f;
#pragma unroll
    for (int i = 0; i < 7; i++) {
        int idx = tid + i * 256;
        float val = (idx < FDIM) ? x[idx] : 0.f;
        v[i] = val; s += val; ss += val * val;
    }
#pragma unroll
    for (int m = 1; m < 64; m <<= 1) { s += __shfl_xor(s, m, 64); ss += __shfl_xor(ss, m, 64); }
    __shared__ float red[8];
    const int w = tid >> 6, lane = tid & 63;
    if (lane == 0) { red[w] = s; red[4 + w] = ss; }
    __syncthreads();
    s = red[0] + red[1] + red[2] + red[3];
    ss = red[4] + red[5] + red[6] + red[7];
    const float mu = s / (float)FDIM;
    const float var = ss / (float)FDIM - mu * mu;
    const float rstd = rsqrtf(var + 1e-5f);
    float a0 = 0.f, a1 = 0.f;
#pragma unroll
    for (int i = 0; i < 7; i++) {
        int idx = tid + i * 256;
        if (idx < FDIM) {
            float nv = (v[i] - mu) * rstd * gam[idx] + bet[idx];
            a0 += nv * Wh[idx * 2];
            a1 += nv * Wh[idx * 2 + 1];
        }
    }
#pragma unroll
    for (int m = 1; m < 64; m <<= 1) { a0 += __shfl_xor(a0, m, 64); a1 += __shfl_xor(a1, m, 64); }
    __shared__ float red2[8];
    if (lane == 0) { red2[w] = a0; red2[4 + w] = a1; }
    __syncthreads();
    if (tid == 0) {
        out[row * 2 + 0] = red2[0] + red2[1] + red2[2] + red2[3] + bh[0];
        out[row * 2 + 1] = red2[4] + red2[5] + red2[6] + red2[7] + bh[1];
    }
}

// ---------------------------------------------------------------- launch
extern "C" void kernel_launch(void* const* d_in, const int* in_sizes, int n_in,
                              void* d_out, int out_size, void* d_ws, size_t ws_size,
                              hipStream_t stream)
{
    const float* t1    = (const float*)d_in[0];
    const float* t2    = (const float*)d_in[1];
    const float* t1c   = (const float*)d_in[2];
    const float* Wqkv1 = (const float*)d_in[3];
    const float* bqkv1 = (const float*)d_in[4];
    const float* Wqkv2 = (const float*)d_in[5];
    const float* bqkv2 = (const float*)d_in[6];
    const float* Wqkv3 = (const float*)d_in[7];
    const float* bqkv3 = (const float*)d_in[8];
    const float* Wo1   = (const float*)d_in[9];
    const float* bo1   = (const float*)d_in[10];
    const float* Wo2   = (const float*)d_in[11];
    const float* bo2   = (const float*)d_in[12];
    const float* Wo3   = (const float*)d_in[13];
    const float* bo3   = (const float*)d_in[14];
    const float* ln_g  = (const float*)d_in[15];
    const float* ln_b  = (const float*)d_in[16];
    const float* Wh    = (const float*)d_in[17];
    const float* bh    = (const float*)d_in[18];

    char* ws = (char*)d_ws;
    size_t off = 0;
    u16* tA    = (u16*)(ws + off); off += (size_t)3 * N_TOK * KPAD * 2;
    u16* WqkvT = (u16*)(ws + off); off += (size_t)3 * OUT3 * KPAD * 2;
    u16* WoT   = (u16*)(ws + off); off += (size_t)3 * DIMF * RDIM * 2;
    u16* qbuf  = (u16*)(ws + off); off += (size_t)3 * N_TOK * OUTD * 2;
    u16* kbuf  = (u16*)(ws + off); off += (size_t)3 * N_TOK * OUTD * 2;
    u16* vT    = (u16*)(ws + off); off += (size_t)3 * OUTD * N_TOK * 2;
    u16* rbuf  = (u16*)(ws + off); off += (size_t)3 * N_TOK * RDIM * 2;
    u16* Opart = (u16*)(ws + off); off += (size_t)NCHUNK * 6 * N_TOK * OUTD * 2;
    float* lpart = (float*)(ws + off); off += (size_t)NCHUNK * 6 * N_TOK * 4;

    float* out  = (float*)d_out;
    float* feat = out + N_TOK * 2;

    prep_tA<<<(3 * N_TOK * KPAD) / 256, 256, 0, stream>>>(t1, t2, t1c, tA);

    transpose_w<<<dim3(12, 9, 3), 256, 0, stream>>>(
        Wqkv1, Wqkv2, Wqkv3, WqkvT, DIMF, OUT3, KPAD);      // [768][544]
    transpose_w<<<dim3(9, 8, 3), 256, 0, stream>>>(
        Wo1, Wo2, Wo3, WoT, RDIM, DIMF, RDIM);              // [514][512]

    qkv_gemm<<<dim3(32, 6, 3), 256, 0, stream>>>(
        tA, WqkvT, bqkv1, bqkv2, bqkv3, qbuf, kbuf, vT);

    attn_kernel<<<dim3(32, 6, NCHUNK), 256, 0, stream>>>(qbuf, kbuf, vT, Opart, lpart);

    combine_kernel<<<dim3(N_TOK, 6), 256, 0, stream>>>(Opart, lpart, kbuf, rbuf);

    proj_gemm<<<dim3(32, 5, 3), 256, 0, stream>>>(
        rbuf, WoT, bo1, bo2, bo3, t1, t2, t1c, feat);

    ln_head<<<4096, 256, 0, stream>>>(feat, ln_g, ln_b, Wh, bh, out);
}